// Round 3
// baseline (515.563 us; speedup 1.0000x reference)
//
#include <hip/hip_runtime.h>

// SSIM (32,3,512,512) fp32, separable 11x11 Gaussian, sqrt-free rational form.
// v10: stop fighting the VGPR occupancy band -- exploit it.
//   v9 post-mortem: h12->LDS did NOT cut VGPR (76->84; compiler spent the
//   headroom). 84 is in the 65..128 band -> HW caps 4 waves/SIMD = 16/CU
//   (m69 quantum). Grid demanded 24/CU -> ragged 16+8 phases -> 28% avg occ,
//   194us. v8(VGPR=40, 69% occ) + v9(84, 28%) pin the cap on VGPR bands.
//   Registers are FREE inside the band, so:
//   1) STRIPE=128: 3072 tiles = 768 WGs x 4 waves = flat 12 waves/CU, zero
//      drain, halo steps amortized 2x (138 steps / 128 output rows).
//   2) h12 ring back in VGPRs (v9's LDS round-trip was pure critical-path
//      cost once it failed to move the VGPR band).
//   3) Drop the per-step "s_waitcnt lgkmcnt(0)" drain: DS ops of one wave
//      execute IN ORDER, so same-wave write->read through LDS needs only a
//      COMPILER fence (v3's failure was compiler hoisting, not HW). The
//      compiler still emits fine-grained lgkmcnt for read-data deps.
//   4) 2-deep global prefetch (row t+2 issued at step t) to cover ~500-900cy
//      load latency; parity-indexed register sets, inner unroll = 22
//      (lcm of ring-11 and parity-2) -> all indices compile-time, and
//      T_MAX = 138 exactly (zero wasted drain steps).
//   Predicted: VGPR 85-105 (<=128!), occ ~37 flat, VALUBusy>=92,
//   main ~100-130us.
// Carried lessons: no waves_per_eu coercion (v2,v5,v6,v8); compiler fence for
// LDS ordering (v3, refined here); readfirstlane is int(int), bit-cast floats
// (v4); 256-bin atomic fan-out (v7); multi-wave WGs for residency (v8);
// VGPR bands 64/128/256 gate waves/SIMD (v9).

#define IMG_H 512
#define IMG_W 512
#define N_IMGS 96                    // 32 batch * 3 channels
#define WAVE_W 64                    // output cols per wave
#define STRIPE 128                   // output rows per wave
#define HALO 5
#define KW 11
#define IN_COLS (WAVE_W + 2*HALO)    // 74
#define N_ROWT (IMG_H / STRIPE)      // 4
#define N_COLT (IMG_W / WAVE_W)      // 8
#define N_TILES (N_IMGS * N_ROWT * N_COLT)   // 3072 tiles, one per wave
#define WPB 4                        // waves (tiles) per workgroup
#define N_BLOCKS (N_TILES / WPB)     // 768 = 3 WGs/CU, 12 waves/CU flat
#define T_STEPS (STRIPE + 2*HALO)    // 138 = 6*22 + 6
#define NBINS 256
#define TOTAL_PIX (32.0f * 3.0f * 512.0f * 512.0f)

__global__ __launch_bounds__(64 * WPB)
void ssim_main(
    const float* __restrict__ img1, const float* __restrict__ img2,
    const float* __restrict__ window, float* __restrict__ bins)
{
    // Per-wave private 2-slot row buffer; no cross-wave sharing.
    __shared__ float2 rowbuf_all[WPB][2][IN_COLS + 2];  // 1216 B/wave

    const int lane = threadIdx.x & 63;     // one output column per lane
    const int wv   = threadIdx.x >> 6;     // wave id within WG -> tile id
    float2 (* __restrict__ rowbuf)[IN_COLS + 2] = rowbuf_all[wv];

    // 1D gaussian, wave-uniform (SGPRs): g[k] = w[5][k] / sqrt(w[5][5]).
    float g[KW];
    {
        const float inv = rsqrtf(window[5*KW + 5]);
        #pragma unroll
        for (int k = 0; k < KW; ++k)
            g[k] = __int_as_float(
                __builtin_amdgcn_readfirstlane(
                    __float_as_int(window[5*KW + k] * inv)));
    }

    const int b   = blockIdx.x * WPB + wv; // tile index 0..3071
    const int img = b >> 5;                // 4x8 = 32 tiles per image
    const int rem = b & 31;
    const int ty  = rem >> 3;              // 0..3 row stripe
    const int tx  = rem & 7;               // 0..7 col stripe
    const int r0  = ty * STRIPE;
    const int x0  = tx * WAVE_W;

    const float* __restrict__ p1 = img1 + (size_t)img * (IMG_H * IMG_W);
    const float* __restrict__ p2 = img2 + (size_t)img * (IMG_H * IMG_W);

    // Staging columns: lane covers row-buffer col lane (gx = x0-5+lane);
    // lanes 0..9 also cover col lane+64.
    const int  gx1  = x0 - HALO + lane;
    const bool c1ok = (unsigned)gx1 < IMG_W;
    const bool tail = lane < (IN_COLS - WAVE_W);    // lanes 0..9
    const int  gx2  = gx1 + WAVE_W;
    const bool c2ok = tail && ((unsigned)gx2 < IMG_W);

    // h-value register ring: 5 signals x 11 slots, all in VGPRs.
    float r_h1[KW], r_h2[KW], r_h11[KW], r_h22[KW], r_h12[KW];
    #pragma unroll
    for (int i = 0; i < KW; ++i) {
        r_h1[i] = 0.f; r_h2[i] = 0.f; r_h11[i] = 0.f; r_h22[i] = 0.f; r_h12[i] = 0.f;
    }

    const float C1 = 1e-4f;   // (0.01*1.0)^2
    const float C2 = 9e-4f;   // (0.03*1.0)^2
    float sum = 0.f;

    // 2-deep prefetch staging, parity-indexed (compile-time in unrolled body).
    float sa[2], sb[2], sa2[2], sb2[2];

#define LOADROW(P, GY) do {                                                  \
        const int gy_ = (GY);                                                \
        sa[P] = 0.f; sb[P] = 0.f; sa2[P] = 0.f; sb2[P] = 0.f;                \
        if ((unsigned)gy_ < IMG_H) {                                         \
            const int base_ = gy_ * IMG_W;                                   \
            if (c1ok) { sa[P]  = p1[base_ + gx1]; sb[P]  = p2[base_ + gx1]; }\
            if (c2ok) { sa2[P] = p1[base_ + gx2]; sb2[P] = p2[base_ + gx2]; }\
        }                                                                    \
    } while (0)

    // Prologue: rows t=0 (set 0) and t=1 (set 1) in flight.
    LOADROW(0, r0 - HALO + 0);
    LOADROW(1, r0 - HALO + 1);

#define STEP(U, TB) do {                                                     \
        const int t_   = (TB) + (U);                                         \
        const int P_   = (U) & 1;            /* compile-time */              \
        const int SL_  = (U) % KW;           /* compile-time */              \
        /* 1) Publish row t from set P. */                                   \
        rowbuf[P_][lane] = make_float2(sa[P_], sb[P_]);                      \
        if (tail) rowbuf[P_][lane + WAVE_W] = make_float2(sa2[P_], sb2[P_]); \
        /* 2) Compiler fence only: same-wave DS ops execute in order. */     \
        asm volatile("" ::: "memory");                                       \
        /* 3) Prefetch row t+2 into set P (just freed). */                   \
        LOADROW(P_, r0 - HALO + t_ + 2);                                     \
        /* 4) Horizontal 11-tap conv from rowbuf[P]. */                      \
        {                                                                    \
            float h1 = 0.f, h2 = 0.f, h11 = 0.f, h22 = 0.f, h12 = 0.f;       \
            _Pragma("unroll")                                                \
            for (int k = 0; k < KW; ++k) {                                   \
                const float2 v = rowbuf[P_][lane + k];                       \
                const float t1 = g[k] * v.x;                                 \
                const float t2 = g[k] * v.y;                                 \
                h1  += t1;                                                   \
                h2  += t2;                                                   \
                h11 += t1 * v.x;                                             \
                h22 += t2 * v.y;                                             \
                h12 += t1 * v.y;                                             \
            }                                                                \
            r_h1[SL_] = h1; r_h2[SL_] = h2; r_h11[SL_] = h11;                \
            r_h22[SL_] = h22; r_h12[SL_] = h12;                              \
        }                                                                    \
        /* 5) Vertical gather + SSIM for output row r0 + t - 10. */          \
        if (t_ >= 2*HALO && t_ < 2*HALO + STRIPE) {                          \
            float mu1 = 0.f, mu2 = 0.f, e11 = 0.f, e22 = 0.f, e12 = 0.f;     \
            _Pragma("unroll")                                                \
            for (int m = 0; m < KW; ++m) {                                   \
                const int slot = (SL_ + 1 + m) % KW;  /* compile-time */     \
                mu1 += g[m] * r_h1[slot];                                    \
                mu2 += g[m] * r_h2[slot];                                    \
                e11 += g[m] * r_h11[slot];                                   \
                e22 += g[m] * r_h22[slot];                                   \
                e12 += g[m] * r_h12[slot];                                   \
            }                                                                \
            const float mu1s = mu1 * mu1, mu2s = mu2 * mu2, mu12 = mu1 * mu2;\
            const float s1  = fmaxf(e11 - mu1s, 0.f);                        \
            const float s2  = fmaxf(e22 - mu2s, 0.f);                        \
            const float s12 = e12 - mu12;                                    \
            const float num = (2.f * mu12 + C1) * (2.f * s12 + C2);          \
            const float den = (mu1s + mu2s + C1) * (s1 + s2 + C2);           \
            sum += num * __builtin_amdgcn_rcpf(den);                         \
        }                                                                    \
    } while (0)

    // Main: 6 blocks of 22 steps (t = 0..131). 22 = lcm(ring 11, parity 2),
    // so ring slot and parity are both compile-time inside the unroll.
    #pragma unroll 1
    for (int tb = 0; tb < 132; tb += 22) {
        #pragma unroll
        for (int u = 0; u < 22; ++u)
            STEP(u, tb);
    }
    // Tail: t = 132..137 (132 % 22 == 0, so slot/parity formulas carry over).
    {
        #pragma unroll
        for (int u = 0; u < 6; ++u)
            STEP(u, 132);
    }
#undef STEP
#undef LOADROW

    // Per-wave reduction -> one atomicAdd per wave, fanned over 256 bins.
    #pragma unroll
    for (int off = 32; off > 0; off >>= 1)
        sum += __shfl_down(sum, off, 64);
    if (lane == 0)
        atomicAdd(&bins[b & (NBINS - 1)], sum);
}

__global__ __launch_bounds__(64) void ssim_final(
    const float* __restrict__ bins, float* __restrict__ out)
{
    const int tid = threadIdx.x;
    float s = 0.f;
    #pragma unroll
    for (int i = 0; i < NBINS / 64; ++i) s += bins[tid + i * 64];
    #pragma unroll
    for (int off = 32; off > 0; off >>= 1)
        s += __shfl_down(s, off, 64);
    if (tid == 0) out[0] = s * (1.0f / TOTAL_PIX);
}

extern "C" void kernel_launch(void* const* d_in, const int* in_sizes, int n_in,
                              void* d_out, int out_size, void* d_ws, size_t ws_size,
                              hipStream_t stream) {
    const float* img1   = (const float*)d_in[0];
    const float* img2   = (const float*)d_in[1];
    const float* window = (const float*)d_in[2];
    float* bins = (float*)d_ws;
    float* out  = (float*)d_out;

    hipMemsetAsync(bins, 0, NBINS * sizeof(float), stream);
    ssim_main<<<N_BLOCKS, 64 * WPB, 0, stream>>>(img1, img2, window, bins);
    ssim_final<<<1, 64, 0, stream>>>(bins, out);
}

// Round 4
// 318.696 us; speedup vs baseline: 1.6177x; 1.6177x over previous
//
#include <hip/hip_runtime.h>

// SSIM (32,3,512,512) fp32, separable 11x11 Gaussian, sqrt-free rational form.
// v11 = v9 loop skeleton + the two ingredients v10 VALIDATED, minus the one
// that killed it.
//   v10 post-mortem: 22-step mega-unroll + 2-deep prefetch -> VGPR 248
//   (129..256 band -> 2 waves/SIMD = 8/CU vs 12 demanded) -> 388us. But v10
//   PROVED (absmax 0.0): (a) fence-only LDS publish is correct -- same-wave
//   DS write->read order is guaranteed by the in-order LDS pipe, no
//   s_waitcnt lgkmcnt(0) drain needed; (b) STRIPE=128 geometry is right.
//   v11: 11-step inner unroll + "#pragma unroll 1" outer (the skeleton that
//   reliably compiles to 76-84 VGPR), STRIPE=128, 1-deep prefetch,
//   fence-only publish.
//   Geometry: 3072 tiles = 768 WGs x 4 waves = 3 WGs/CU = 12 waves/CU,
//   under the 16/CU cap of the 65..128 VGPR band -> whole grid resident,
//   ZERO drain, flat occupancy ~37%. T_MAX=143 (13*11), 5 drain steps (3.5%).
//   Predicted: VGPR 75-100 (gate!), occ ~37 flat, VALUBusy>=88,
//   main 75-110us.
// Carried lessons: no waves_per_eu coercion (v2,v5,v6,v8); fence-only LDS
// publish, validated v10 (supersedes v3); readfirstlane is int(int), bit-cast
// floats (v4); 256-bin atomic fan-out (v7); multi-wave WGs for residency
// (v8); VGPR bands 64/128/256 gate waves/SIMD (v9,v10); unroll width inflates
// VGPR -- keep inner unroll at 11 (v10).

#define IMG_H 512
#define IMG_W 512
#define N_IMGS 96                    // 32 batch * 3 channels
#define WAVE_W 64                    // output cols per wave
#define STRIPE 128                   // output rows per wave
#define HALO 5
#define KW 11
#define IN_COLS (WAVE_W + 2*HALO)    // 74
#define N_ROWT (IMG_H / STRIPE)      // 4
#define N_COLT (IMG_W / WAVE_W)      // 8
#define N_TILES (N_IMGS * N_ROWT * N_COLT)   // 3072 tiles, one per wave
#define WPB 4                        // waves (tiles) per workgroup
#define N_BLOCKS (N_TILES / WPB)     // 768 = 3 WGs/CU, 12 waves/CU flat
#define T_MAX 143                    // 13*11; t=138..142 are drain no-ops
#define NBINS 256
#define TOTAL_PIX (32.0f * 3.0f * 512.0f * 512.0f)

__global__ __launch_bounds__(64 * WPB)
void ssim_main(
    const float* __restrict__ img1, const float* __restrict__ img2,
    const float* __restrict__ window, float* __restrict__ bins)
{
    // Per-wave private 2-slot row buffer; no cross-wave sharing.
    __shared__ float2 rowbuf_all[WPB][2][IN_COLS + 2];  // 1216 B/wave

    const int lane = threadIdx.x & 63;     // one output column per lane
    const int wv   = threadIdx.x >> 6;     // wave id within WG -> tile id
    float2 (* __restrict__ rowbuf)[IN_COLS + 2] = rowbuf_all[wv];

    // 1D gaussian, wave-uniform (SGPRs): g[k] = w[5][k] / sqrt(w[5][5]).
    float g[KW];
    {
        const float inv = rsqrtf(window[5*KW + 5]);
        #pragma unroll
        for (int k = 0; k < KW; ++k)
            g[k] = __int_as_float(
                __builtin_amdgcn_readfirstlane(
                    __float_as_int(window[5*KW + k] * inv)));
    }

    const int b   = blockIdx.x * WPB + wv; // tile index 0..3071
    const int img = b >> 5;                // 4x8 = 32 tiles per image
    const int rem = b & 31;
    const int ty  = rem >> 3;              // 0..3 row stripe
    const int tx  = rem & 7;               // 0..7 col stripe
    const int r0  = ty * STRIPE;
    const int x0  = tx * WAVE_W;

    const float* __restrict__ p1 = img1 + (size_t)img * (IMG_H * IMG_W);
    const float* __restrict__ p2 = img2 + (size_t)img * (IMG_H * IMG_W);

    // Staging columns: lane covers row-buffer col lane (gx = x0-5+lane);
    // lanes 0..9 also cover col lane+64.
    const int  gx1  = x0 - HALO + lane;
    const bool c1ok = (unsigned)gx1 < IMG_W;
    const bool tail = lane < (IN_COLS - WAVE_W);    // lanes 0..9
    const int  gx2  = gx1 + WAVE_W;
    const bool c2ok = tail && ((unsigned)gx2 < IMG_W);

    // h-value register ring: 5 signals x 11 slots, all in VGPRs.
    float r_h1[KW], r_h2[KW], r_h11[KW], r_h22[KW], r_h12[KW];
    #pragma unroll
    for (int i = 0; i < KW; ++i) {
        r_h1[i] = 0.f; r_h2[i] = 0.f; r_h11[i] = 0.f; r_h22[i] = 0.f; r_h12[i] = 0.f;
    }

    const float C1 = 1e-4f;   // (0.01*1.0)^2
    const float C2 = 9e-4f;   // (0.03*1.0)^2
    float sum = 0.f;

    // Prologue: load input row t=0 (gy = r0-5) into staging registers.
    float sa = 0.f, sb = 0.f, sa2 = 0.f, sb2 = 0.f;
    {
        const int gy = r0 - HALO;
        if ((unsigned)gy < IMG_H) {
            const int base = gy * IMG_W;
            if (c1ok) { sa  = p1[base + gx1]; sb  = p2[base + gx1]; }
            if (c2ok) { sa2 = p1[base + gx2]; sb2 = p2[base + gx2]; }
        }
    }

    #pragma unroll 1
    for (int tb = 0; tb < T_MAX; tb += KW) {
        #pragma unroll
        for (int u = 0; u < KW; ++u) {       // t % 11 == u, static slots
            const int t = tb + u;

            // 1) Publish row t into row-buffer slot (u&1).
            rowbuf[u & 1][lane] = make_float2(sa, sb);
            if (tail) rowbuf[u & 1][lane + WAVE_W] = make_float2(sa2, sb2);

            // 2) Compiler fence only (validated v10): same-wave DS ops
            //    execute in order in the LDS pipe; just stop the compiler
            //    from hoisting the ds_reads above the ds_writes.
            asm volatile("" ::: "memory");

            // 3) Issue global loads for row t+1 (consumed at next publish).
            {
                const int gy = r0 - HALO + t + 1;
                sa = 0.f; sb = 0.f; sa2 = 0.f; sb2 = 0.f;
                if ((unsigned)gy < IMG_H) {
                    const int base = gy * IMG_W;
                    if (c1ok) { sa  = p1[base + gx1]; sb  = p2[base + gx1]; }
                    if (c2ok) { sa2 = p1[base + gx2]; sb2 = p2[base + gx2]; }
                }
            }

            // 4) Horizontal 11-tap conv at col x0+lane from the row buffer.
            float h1 = 0.f, h2 = 0.f, h11 = 0.f, h22 = 0.f, h12 = 0.f;
            #pragma unroll
            for (int k = 0; k < KW; ++k) {
                const float2 v = rowbuf[u & 1][lane + k];
                const float t1 = g[k] * v.x;
                const float t2 = g[k] * v.y;
                h1  += t1;
                h2  += t2;
                h11 += t1 * v.x;
                h22 += t2 * v.y;
                h12 += t1 * v.y;
            }
            r_h1[u] = h1; r_h2[u] = h2; r_h11[u] = h11; r_h22[u] = h22; r_h12[u] = h12;

            // 5) Vertical gather + SSIM for output row r0 + t - 10
            //    (uniform branch: t depends only on tb/u).
            if (t >= 2*HALO && t < 2*HALO + STRIPE) {
                float mu1 = 0.f, mu2 = 0.f, e11 = 0.f, e22 = 0.f, e12 = 0.f;
                #pragma unroll
                for (int m = 0; m < KW; ++m) {
                    const int slot = (u + 1 + m) % KW;  // compile-time index
                    mu1 += g[m] * r_h1[slot];
                    mu2 += g[m] * r_h2[slot];
                    e11 += g[m] * r_h11[slot];
                    e22 += g[m] * r_h22[slot];
                    e12 += g[m] * r_h12[slot];
                }
                const float mu1s = mu1 * mu1, mu2s = mu2 * mu2, mu12 = mu1 * mu2;
                const float s1  = fmaxf(e11 - mu1s, 0.f);
                const float s2  = fmaxf(e22 - mu2s, 0.f);
                const float s12 = e12 - mu12;
                const float num = (2.f * mu12 + C1) * (2.f * s12 + C2);
                const float den = (mu1s + mu2s + C1) * (s1 + s2 + C2);
                sum += num * __builtin_amdgcn_rcpf(den);
            }
        }
    }

    // Per-wave reduction -> one atomicAdd per wave, fanned over 256 bins.
    #pragma unroll
    for (int off = 32; off > 0; off >>= 1)
        sum += __shfl_down(sum, off, 64);
    if (lane == 0)
        atomicAdd(&bins[b & (NBINS - 1)], sum);
}

__global__ __launch_bounds__(64) void ssim_final(
    const float* __restrict__ bins, float* __restrict__ out)
{
    const int tid = threadIdx.x;
    float s = 0.f;
    #pragma unroll
    for (int i = 0; i < NBINS / 64; ++i) s += bins[tid + i * 64];
    #pragma unroll
    for (int off = 32; off > 0; off >>= 1)
        s += __shfl_down(s, off, 64);
    if (tid == 0) out[0] = s * (1.0f / TOTAL_PIX);
}

extern "C" void kernel_launch(void* const* d_in, const int* in_sizes, int n_in,
                              void* d_out, int out_size, void* d_ws, size_t ws_size,
                              hipStream_t stream) {
    const float* img1   = (const float*)d_in[0];
    const float* img2   = (const float*)d_in[1];
    const float* window = (const float*)d_in[2];
    float* bins = (float*)d_ws;
    float* out  = (float*)d_out;

    hipMemsetAsync(bins, 0, NBINS * sizeof(float), stream);
    ssim_main<<<N_BLOCKS, 64 * WPB, 0, stream>>>(img1, img2, window, bins);
    ssim_final<<<1, 64, 0, stream>>>(bins, out);
}